// Round 7
// baseline (57.353 us; speedup 1.0000x reference)
//
#include <hip/hip_runtime.h>
#include <hip/hip_fp16.h>

// QuantLinear: out[16][11008] = x[16][4096] . dequant(weight_q[11008][4096])^T + bias
// Harness promotes fp16 tensors to fp32 -> x/scale/zero/bias are float*.
// Round-6 lesson: ~51us invariant to waves/CU (10.75 / 21.5 / 43) -> NOT
// occupancy/MLP-bound. Theory: scattered weight loads (each instr = 16 rows
// 16KB apart = 16 scattered lines) cap per-CU load throughput at ~5.7 B/cy;
// contiguous-stream patterns (fills, float4 copy) do 25+ B/cy.
// This round: wave-contiguous 1KB global_load_lds staging of weight tiles into
// double-buffered swizzled LDS (T21: linear dest + inverse-swizzled source +
// swizzled ds_read_b128). 688 blocks x 4 waves, K-step 256 ints, 36KB LDS.

typedef _Float16 v8hf __attribute__((ext_vector_type(8)));
typedef float v4f __attribute__((ext_vector_type(4)));

#define O_DIM 11008
#define I_DIM 4096
#define NGROUP 32   // I_DIM / 128
#define KSTEP 256   // ints per K-step (1 KB per row)
#define NSTEP 16    // I_DIM / KSTEP

__global__ __launch_bounds__(256) void qgemm(const float* __restrict__ x,
                                             const int* __restrict__ wq,
                                             const float* __restrict__ scale,
                                             const float* __restrict__ zero,
                                             const float* __restrict__ bias,
                                             float* __restrict__ out) {
    __shared__ int   wtile[2][16][KSTEP];   // 2 x 16 KB, 16B-unit XOR-swizzled per row
    __shared__ float red[4][256];

    const int ot  = blockIdx.x;    // o-tile 0..687
    const int tid = threadIdx.x;
    const int w   = tid >> 6;      // wave 0..3
    const int l   = tid & 63;
    const int col = l & 15;        // A-row = x-row / B-col = o (within tile)
    const int kb  = l >> 4;        // k sub-block 0..3
    const int o   = ot * 16 + col;

    // Staging: wave w stages rows 4w..4w+3. Lane l supplies the 16B unit that
    // must land at LDS position l (HW writes base + lane*16), i.e. global unit
    // l ^ (r&7)  (XOR is an involution; reader applies the same XOR).
    size_t wbase[4];
#pragma unroll
    for (int rr = 0; rr < 4; ++rr) {
        const int r = w * 4 + rr;
        wbase[rr] = (size_t)(ot * 16 + r) * I_DIM + ((l ^ (r & 7)) << 2); // ints
    }

    const float* __restrict__ xrow = x + (size_t)col * I_DIM;
    const int grp_half = w >> 1;     // group within the step's 2 (w<2 -> 0)
    const int kk = w * 64;           // this wave's k-window base within a step

    v4f acc = {0.f, 0.f, 0.f, 0.f};

    // prologue: stage step 0 into buffer 0
#pragma unroll
    for (int rr = 0; rr < 4; ++rr) {
        const int r = w * 4 + rr;
        __builtin_amdgcn_global_load_lds(
            (const __attribute__((address_space(1))) void*)(wq + wbase[rr]),
            (__attribute__((address_space(3))) void*)&wtile[0][r][0], 16, 0, 0);
    }
    asm volatile("s_waitcnt vmcnt(0)");
    __syncthreads();

    for (int t = 0; t < NSTEP; ++t) {
        const int tb = t & 1;
        // issue next step's stage early (targets the other buffer)
        if (t + 1 < NSTEP) {
#pragma unroll
            for (int rr = 0; rr < 4; ++rr) {
                const int r = w * 4 + rr;
                __builtin_amdgcn_global_load_lds(
                    (const __attribute__((address_space(1))) void*)
                        (wq + wbase[rr] + (size_t)(t + 1) * KSTEP),
                    (__attribute__((address_space(3))) void*)&wtile[tb ^ 1][r][0],
                    16, 0, 0);
            }
        }

        const int g = t * 2 + grp_half;          // scale group for this wave
        const float s   = scale[o * NGROUP + g];
        const float z   = zero [o * NGROUP + g];
        const float nzs = -z * s;
        const char* lrow = (const char*)&wtile[tb][col][0];

#pragma unroll
        for (int m = 0; m < 2; ++m) {
            const int u0 = ((kk + m * 32) >> 2) + kb * 2;   // even 16B unit
            const int4 q0 = *(const int4*)(lrow + (((u0    ) ^ (col & 7)) << 4));
            const int4 q1 = *(const int4*)(lrow + (((u0 + 1) ^ (col & 7)) << 4));
            const float* xp = xrow + t * KSTEP + kk + m * 32 + kb * 8;
            const float4 x0 = *(const float4*)(xp);
            const float4 x1 = *(const float4*)(xp + 4);
            v8hf a;
            a[0] = (_Float16)x0.x; a[1] = (_Float16)x0.y;
            a[2] = (_Float16)x0.z; a[3] = (_Float16)x0.w;
            a[4] = (_Float16)x1.x; a[5] = (_Float16)x1.y;
            a[6] = (_Float16)x1.z; a[7] = (_Float16)x1.w;
            v8hf bf;   // same (lane,j)->k mapping as A => permutation cancels
            bf[0] = (_Float16)((float)(q0.x & 255) * s + nzs);
            bf[1] = (_Float16)((float)(q0.y & 255) * s + nzs);
            bf[2] = (_Float16)((float)(q0.z & 255) * s + nzs);
            bf[3] = (_Float16)((float)(q0.w & 255) * s + nzs);
            bf[4] = (_Float16)((float)(q1.x & 255) * s + nzs);
            bf[5] = (_Float16)((float)(q1.y & 255) * s + nzs);
            bf[6] = (_Float16)((float)(q1.z & 255) * s + nzs);
            bf[7] = (_Float16)((float)(q1.w & 255) * s + nzs);
            acc = __builtin_amdgcn_mfma_f32_16x16x32_f16(a, bf, acc, 0, 0, 0);
        }

        // next-buffer stage complete + all waves done reading this buffer
        asm volatile("s_waitcnt vmcnt(0)");
        __syncthreads();
    }

    // Cross-wave K-reduce. acc[r] = tile element (row=(l>>4)*4+r, col=l&15).
    *(v4f*)&red[w][l * 4] = acc;
    __syncthreads();

    const int t2  = tid;
    const float sum = red[0][t2] + red[1][t2] + red[2][t2] + red[3][t2];
    const int l2  = t2 >> 2;
    const int r   = t2 & 3;
    const int row = (l2 >> 4) * 4 + r;      // x-row 0..15
    const int oc  = ot * 16 + (l2 & 15);    // output column
    out[(size_t)row * O_DIM + oc] = sum + bias[oc];
}

extern "C" void kernel_launch(void* const* d_in, const int* in_sizes, int n_in,
                              void* d_out, int out_size, void* d_ws, size_t ws_size,
                              hipStream_t stream) {
    const float* x   = (const float*)d_in[0];
    const int*   wqp = (const int*)  d_in[1];
    const float* sc  = (const float*)d_in[2];
    const float* zp  = (const float*)d_in[3];
    const float* bp  = (const float*)d_in[4];
    float* out = (float*)d_out;

    qgemm<<<688, 256, 0, stream>>>(x, wqp, sc, zp, bp, out);
}